// Round 3
// baseline (243.848 us; speedup 1.0000x reference)
//
#include <hip/hip_runtime.h>

typedef float  f32x4 __attribute__((ext_vector_type(4)));
typedef float  f32x2 __attribute__((ext_vector_type(2)));
typedef short  short8v __attribute__((ext_vector_type(8)));

static __device__ __forceinline__ unsigned short f2bf(float f) {
  union { float f; unsigned u; } v; v.f = f;
  unsigned r = v.u + 0x7FFFu + ((v.u >> 16) & 1u);   // RNE
  return (unsigned short)(r >> 16);
}
static __device__ __forceinline__ float bf2f(unsigned short h) {
  union { unsigned u; float f; } v; v.u = ((unsigned)h) << 16;
  return v.f;
}
static __device__ __forceinline__ f32x4 mfma16(short8v a, short8v b, f32x4 c) {
  return __builtin_amdgcn_mfma_f32_16x16x32_bf16(a, b, c, 0, 0, 0);
}

// ---- window-of-4 loaders (c0 even, no wrap) ----
static __device__ __forceinline__ float win4(const float* row, int c0) {
  f32x2 u = *(const f32x2*)(row + c0);
  f32x2 w = *(const f32x2*)(row + c0 + 2);
  return u[0] + u[1] + w[0] + w[1];
}
static __device__ __forceinline__ float win4(const unsigned short* row, int c0) {
  unsigned a = *(const unsigned*)(row + c0);
  unsigned b = *(const unsigned*)(row + c0 + 2);
  return bf2f((unsigned short)a) + bf2f((unsigned short)(a >> 16)) +
         bf2f((unsigned short)b) + bf2f((unsigned short)(b >> 16));
}
static __device__ __forceinline__ float elt(const float* r, int c) { return r[c]; }
static __device__ __forceinline__ float elt(const unsigned short* r, int c) { return bf2f(r[c]); }

// ---- fused adj pooling + rowsum + diag extract.
// out[j,k] = sum_{a,b in 0..3} in[(2j+a)%nin][(2k+b)%nin] (bf16)
// rs[j] = f32 rowsum of out row j; diag[j] = f32 out[j,j].
// Block: 8 rows x full width; threads (jj 0..7, kk 0..31).
template <typename T>
__global__ __launch_bounds__(256) void pool_adj_rs_kernel(const T* __restrict__ in,
                                                          unsigned short* __restrict__ outh,
                                                          float* __restrict__ rs,
                                                          float* __restrict__ diag,
                                                          int n, int nin) {
  int jj = threadIdx.x >> 5, kk = threadIdx.x & 31;
  int j = blockIdx.x * 8 + jj;
  int r0 = 2 * j;
  const T* row0 = in + (size_t)((r0 + 0) & (nin - 1)) * nin;
  const T* row1 = in + (size_t)((r0 + 1) & (nin - 1)) * nin;
  const T* row2 = in + (size_t)((r0 + 2) & (nin - 1)) * nin;
  const T* row3 = in + (size_t)((r0 + 3) & (nin - 1)) * nin;
  float racc = 0.f, dval = 0.f;
  for (int k = kk; k < n; k += 32) {
    int c0 = 2 * k;
    float s;
    if (c0 + 3 < nin) {
      s = win4(row0, c0) + win4(row1, c0) + win4(row2, c0) + win4(row3, c0);
    } else {
      s = 0.f;
      #pragma unroll
      for (int b = 0; b < 4; ++b) {
        int c = (c0 + b) & (nin - 1);
        s += elt(row0, c) + elt(row1, c) + elt(row2, c) + elt(row3, c);
      }
    }
    outh[(size_t)j * n + k] = f2bf(s);
    racc += s;
    if (k == j) dval = s;
  }
  #pragma unroll
  for (int o = 16; o > 0; o >>= 1) racc += __shfl_xor(racc, o);
  #pragma unroll
  for (int o = 16; o > 0; o >>= 1) dval += __shfl_xor(dval, o);
  if (kk == 0) { rs[j] = racc; diag[j] = dval; }
}

// ---- emit bf16 hi/lo of X and transposed bf16 hi (for K and V^T)
__global__ __launch_bounds__(256) void split_transpose_kernel(const float* __restrict__ X,
                                                              unsigned short* __restrict__ Oh,
                                                              unsigned short* __restrict__ Ol,
                                                              unsigned short* __restrict__ OT,
                                                              int M) {
  __shared__ unsigned short t[32][33];
  int i0 = blockIdx.x * 32, d0 = blockIdx.y * 32;
  int tx = threadIdx.x & 31, ty = threadIdx.x >> 5;
  #pragma unroll
  for (int rr = 0; rr < 4; ++rr) {
    int i = i0 + ty + rr * 8;
    int d = d0 + tx;
    float v = X[(size_t)i * 128 + d];
    unsigned short hi = f2bf(v);
    Oh[(size_t)i * 128 + d] = hi;
    Ol[(size_t)i * 128 + d] = f2bf(v - bf2f(hi));
    t[ty + rr * 8][tx] = hi;
  }
  __syncthreads();
  #pragma unroll
  for (int rr = 0; rr < 4; ++rr) {
    int d = d0 + ty + rr * 8;
    int i = i0 + tx;
    OT[(size_t)d * M + i] = t[tx][ty + rr * 8];
  }
}

// ---- shared 16x128 @ 128x128 gemm body (xs in LDS, thread owns col d)
static __device__ __forceinline__ void gemm16x128(const float (*xs)[128],
                                                  const float* __restrict__ W,
                                                  int d, float* acc) {
  #pragma unroll
  for (int i = 0; i < 16; ++i) acc[i] = 0.f;
  for (int e = 0; e < 128; e += 4) {
    float w0 = W[(e + 0) * 128 + d];
    float w1 = W[(e + 1) * 128 + d];
    float w2 = W[(e + 2) * 128 + d];
    float w3 = W[(e + 3) * 128 + d];
    #pragma unroll
    for (int i = 0; i < 16; ++i) {
      f32x4 xv = *(const f32x4*)&xs[i][e];
      float a = acc[i];
      a = fmaf(xv[0], w0, a);
      a = fmaf(xv[1], w1, a);
      a = fmaf(xv[2], w2, a);
      a = fmaf(xv[3], w3, a);
      acc[i] = a;
    }
  }
}

// ---- x1b = row-pool(x); Q = x1b @ ca1 split to bf16 hi/lo
__global__ __launch_bounds__(128) void gemm_q_kernel(const float* __restrict__ x,
                                                     const float* __restrict__ W,
                                                     float* __restrict__ x1b,
                                                     unsigned short* __restrict__ Qh,
                                                     unsigned short* __restrict__ Ql) {
  __shared__ float xs[16][128];
  int r0 = blockIdx.x * 16;
  int d = threadIdx.x;
  #pragma unroll
  for (int i = 0; i < 16; ++i) {
    int rr = 2 * (r0 + i);
    float v = x[(size_t)((rr + 0) & 4095) * 128 + d] + x[(size_t)((rr + 1) & 4095) * 128 + d] +
              x[(size_t)((rr + 2) & 4095) * 128 + d] + x[(size_t)((rr + 3) & 4095) * 128 + d];
    xs[i][d] = v;
    x1b[(size_t)(r0 + i) * 128 + d] = v;
  }
  __syncthreads();
  float acc[16];
  gemm16x128(xs, W, d, acc);
  #pragma unroll
  for (int i = 0; i < 16; ++i) {
    size_t o = (size_t)(r0 + i) * 128 + d;
    unsigned short hi = f2bf(acc[i]);
    Qh[o] = hi;
    Ql[o] = f2bf(acc[i] - bf2f(hi));
  }
}

// ---- split-K flash attention partials (bf16x3 QK^T, masked-to-zero scores).
// Block (jt,kc): q-rows jt*16..+15 over k-range kc*256..+255, 1 wave.
// S computed transposed (A=K tile, B=Q^T) so lane owns q = lane&15.
__global__ __launch_bounds__(64) void flash_kernel(const unsigned short* __restrict__ Qh,
                                                   const unsigned short* __restrict__ Ql,
                                                   const unsigned short* __restrict__ Kh,
                                                   const unsigned short* __restrict__ Kl,
                                                   const unsigned short* __restrict__ VT,
                                                   unsigned short* __restrict__ pacc,
                                                   float* __restrict__ pm,
                                                   float* __restrict__ pl) {
  int bid = blockIdx.x;
  int jt = bid >> 4, kc = bid & 15;
  int lane = threadIdx.x;
  int q = lane & 15, g = lane >> 4;
  int j = jt * 16 + q;
  int kbase = kc * 256;
  int twoj = 2 * j;
  __shared__ unsigned short P[16][32];

  short8v qh[4], ql[4];
  #pragma unroll
  for (int c = 0; c < 4; ++c) {
    qh[c] = *(const short8v*)&Qh[(size_t)j * 128 + c * 32 + g * 8];
    ql[c] = *(const short8v*)&Ql[(size_t)j * 128 + c * 32 + g * 8];
  }
  float m = -1e30f, l = 0.f;
  f32x4 acc[8];
  #pragma unroll
  for (int t = 0; t < 8; ++t) acc[t] = (f32x4){0.f, 0.f, 0.f, 0.f};

  for (int step = 0; step < 8; ++step) {
    int kt = kbase + step * 32;
    const unsigned short* ka_h = Kh + (size_t)(kt + q) * 128;
    const unsigned short* ka_l = Kl + (size_t)(kt + q) * 128;
    const unsigned short* kb_h = ka_h + 16 * 128;
    const unsigned short* kb_l = ka_l + 16 * 128;
    f32x4 z = {0.f, 0.f, 0.f, 0.f};
    f32x4 hh0 = z, hl0 = z, lh0 = z, hh1 = z, hl1 = z, lh1 = z;
    __builtin_amdgcn_s_setprio(1);
    #pragma unroll
    for (int c = 0; c < 4; ++c) {
      int off = c * 32 + g * 8;
      short8v ah = *(const short8v*)(ka_h + off);
      short8v al = *(const short8v*)(ka_l + off);
      short8v bh = *(const short8v*)(kb_h + off);
      short8v bl = *(const short8v*)(kb_l + off);
      hh0 = mfma16(ah, qh[c], hh0);   // 6 independent 4-deep chains
      hh1 = mfma16(bh, qh[c], hh1);
      hl0 = mfma16(ah, ql[c], hl0);
      hl1 = mfma16(bh, ql[c], hl1);
      lh0 = mfma16(al, qh[c], lh0);
      lh1 = mfma16(bl, qh[c], lh1);
    }
    __builtin_amdgcn_s_setprio(0);
    // prefetch V fragments now: consumed only after softmax, hides L2 latency
    short8v vfrag[8];
    const unsigned short* vb = VT + kt + g * 8;
    #pragma unroll
    for (int t = 0; t < 8; ++t)
      vfrag[t] = *(const short8v*)(vb + (size_t)(t * 16 + q) * 4096);

    f32x4 s0 = hh0 + hl0 + lh0;
    f32x4 s1 = hh1 + hl1 + lh1;
    float sv[8];
    #pragma unroll
    for (int r = 0; r < 4; ++r) {
      int k0 = kt + g * 4 + r;          // D row = k-within-tile = 4g+r
      float v0 = s0[r];
      if (((k0 - twoj) & 4095) < 4) v0 = 0.f;
      sv[r] = v0;
      int k1 = k0 + 16;
      float v1 = s1[r];
      if (((k1 - twoj) & 4095) < 4) v1 = 0.f;
      sv[4 + r] = v1;
    }
    float cmx = sv[0];
    #pragma unroll
    for (int r = 1; r < 8; ++r) cmx = fmaxf(cmx, sv[r]);
    cmx = fmaxf(cmx, __shfl_xor(cmx, 16));
    cmx = fmaxf(cmx, __shfl_xor(cmx, 32));
    float mnew = fmaxf(m, cmx);
    float ps = 0.f;
    unsigned short pb[8];
    #pragma unroll
    for (int r = 0; r < 8; ++r) {
      float pv = __expf(sv[r] - mnew);
      ps += pv;
      pb[r] = f2bf(pv);
    }
    ps += __shfl_xor(ps, 16);
    ps += __shfl_xor(ps, 32);
    if (__any(cmx > m)) {               // defer-rescale: skip when max didn't grow
      float scl = __expf(m - mnew);
      l *= scl;
      float sc0 = __shfl(scl, 4 * g + 0);
      float sc1 = __shfl(scl, 4 * g + 1);
      float sc2 = __shfl(scl, 4 * g + 2);
      float sc3 = __shfl(scl, 4 * g + 3);
      #pragma unroll
      for (int t = 0; t < 8; ++t) {
        acc[t][0] *= sc0; acc[t][1] *= sc1; acc[t][2] *= sc2; acc[t][3] *= sc3;
      }
    }
    m = mnew;
    l += ps;
    // write P[q][k_local]: tile a k_local=4g+r, tile b 16+4g+r (packed pairs)
    *(unsigned*)&P[q][4 * g]          = (unsigned)pb[0] | ((unsigned)pb[1] << 16);
    *(unsigned*)&P[q][4 * g + 2]      = (unsigned)pb[2] | ((unsigned)pb[3] << 16);
    *(unsigned*)&P[q][16 + 4 * g]     = (unsigned)pb[4] | ((unsigned)pb[5] << 16);
    *(unsigned*)&P[q][16 + 4 * g + 2] = (unsigned)pb[6] | ((unsigned)pb[7] << 16);
    __syncthreads();
    short8v pa = *(const short8v*)&P[q][8 * g];   // A-frag: row q, k=8g+e
    __builtin_amdgcn_s_setprio(1);
    #pragma unroll
    for (int t = 0; t < 8; ++t) acc[t] = mfma16(pa, vfrag[t], acc[t]);
    __builtin_amdgcn_s_setprio(0);
    __syncthreads();
  }
  #pragma unroll
  for (int t = 0; t < 8; ++t) {
    #pragma unroll
    for (int r = 0; r < 4; ++r)
      pacc[((size_t)(jt * 16 + g * 4 + r) * 16 + kc) * 128 + t * 16 + q] = f2bf(acc[t][r]);
  }
  if (g == 0) {
    pm[(size_t)j * 16 + kc] = m;
    pl[(size_t)j * 16 + kc] = l;
  }
}

// ---- merge split-K partials -> x1 = alpha@x + x1b (LDS); y = d1.*(x1@W1); yT bf16
__global__ __launch_bounds__(128) void combine_gemm_kernel(const unsigned short* __restrict__ pacc,
                                                           const float* __restrict__ pm,
                                                           const float* __restrict__ pl,
                                                           const float* __restrict__ x1b,
                                                           const float* __restrict__ W,
                                                           const float* __restrict__ rs,
                                                           const float* __restrict__ diag,
                                                           float* __restrict__ yB,
                                                           unsigned short* __restrict__ YT,
                                                           int M) {
  __shared__ float xs[16][128];
  int r0 = blockIdx.x * 16;
  int d = threadIdx.x;
  #pragma unroll
  for (int i = 0; i < 16; ++i) {
    int j = r0 + i;
    float Mx = -1e30f;
    #pragma unroll
    for (int c = 0; c < 16; ++c) Mx = fmaxf(Mx, pm[(size_t)j * 16 + c]);
    float L = 0.f, o = 0.f;
    for (int c = 0; c < 16; ++c) {
      float w = __expf(pm[(size_t)j * 16 + c] - Mx);
      L += pl[(size_t)j * 16 + c] * w;
      o += w * bf2f(pacc[((size_t)j * 16 + c) * 128 + d]);
    }
    xs[i][d] = o / L + x1b[(size_t)j * 128 + d];
  }
  __syncthreads();
  float acc[16];
  gemm16x128(xs, W, d, acc);
  short8v t0, t1;
  #pragma unroll
  for (int i = 0; i < 16; ++i) {
    int j = r0 + i;
    float dv = rsqrtf(fmaxf(rs[j] - diag[j] + 1.f, 1.f));
    float v = acc[i] * dv;
    yB[(size_t)j * 128 + d] = v;
    if (i < 8) t0[i] = (short)f2bf(v); else t1[i - 8] = (short)f2bf(v);
  }
  *(short8v*)&YT[(size_t)d * M + r0] = t0;
  *(short8v*)&YT[(size_t)d * M + r0 + 8] = t1;
}

// ---- C_ks[M,128] partial = A_bf16[M, K-half] @ B, B transposed bf16 BT[128,K]
__global__ __launch_bounds__(64) void mfma_gemm_kernel(const unsigned short* __restrict__ A,
                                                       const unsigned short* __restrict__ BT,
                                                       float* __restrict__ C, int K, int M) {
  int jt = blockIdx.x, nt = blockIdx.y, ks = blockIdx.z;
  int lane = threadIdx.x;
  int q = lane & 15, g = lane >> 4;
  const unsigned short* arow = A + (size_t)(jt * 16 + q) * K;
  const unsigned short* brow = BT + (size_t)(nt * 16 + q) * K;
  int kbeg = ks * (K >> 1), kend = kbeg + (K >> 1);
  f32x4 acc = {0.f, 0.f, 0.f, 0.f};
  for (int k0 = kbeg; k0 < kend; k0 += 32) {
    int ka = k0 + g * 8;
    short8v af = *(const short8v*)(arow + ka);
    short8v bf = *(const short8v*)(brow + ka);
    acc = mfma16(af, bf, acc);
  }
  float* Cp = C + (size_t)ks * M * 128;
  #pragma unroll
  for (int r = 0; r < 4; ++r)
    Cp[(size_t)(jt * 16 + g * 4 + r) * 128 + nt * 16 + q] = acc[r];
}

// ---- GCN epilogue element: h[r][d] (G = 2 K-split partials, n rows each)
static __device__ __forceinline__ float epi_h(const float* __restrict__ G,
                                              const float* __restrict__ y,
                                              const float* __restrict__ rs,
                                              const float* __restrict__ diag,
                                              const float* __restrict__ bias,
                                              int n, int r, int d, bool relu) {
  float dv = rsqrtf(fmaxf(rs[r] - diag[r] + 1.f, 1.f));
  float gs = G[(size_t)r * 128 + d] + G[(size_t)(n + r) * 128 + d];
  float v = dv * (gs + (1.f - diag[r]) * y[(size_t)r * 128 + d]) + bias[d];
  return relu ? fmaxf(v, 0.f) : v;
}

// ---- x2 = row-pool(relu-gcn-epi(level1)); y2 = d2.*(x2@W2); y2T bf16
__global__ __launch_bounds__(128) void epi_pool_gemm_kernel(const float* __restrict__ G,
                                                            const float* __restrict__ yB,
                                                            const float* __restrict__ rs1,
                                                            const float* __restrict__ diag1,
                                                            const float* __restrict__ b1,
                                                            const float* __restrict__ W,
                                                            const float* __restrict__ rs2,
                                                            const float* __restrict__ diag2,
                                                            float* __restrict__ y2B,
                                                            unsigned short* __restrict__ Y2T,
                                                            int n1, int M2) {
  __shared__ float xs[16][128];
  int r0 = blockIdx.x * 16;
  int d = threadIdx.x;
  #pragma unroll
  for (int i = 0; i < 16; ++i) {
    int rr = 2 * (r0 + i);
    float s = 0.f;
    #pragma unroll
    for (int a = 0; a < 4; ++a)
      s += epi_h(G, yB, rs1, diag1, b1, n1, (rr + a) & (n1 - 1), d, true);
    xs[i][d] = s;
  }
  __syncthreads();
  float acc[16];
  gemm16x128(xs, W, d, acc);
  short8v t0, t1;
  #pragma unroll
  for (int i = 0; i < 16; ++i) {
    int j = r0 + i;
    float dv = rsqrtf(fmaxf(rs2[j] - diag2[j] + 1.f, 1.f));
    float v = acc[i] * dv;
    y2B[(size_t)j * 128 + d] = v;
    if (i < 8) t0[i] = (short)f2bf(v); else t1[i - 8] = (short)f2bf(v);
  }
  *(short8v*)&Y2T[(size_t)d * M2 + r0] = t0;
  *(short8v*)&Y2T[(size_t)d * M2 + r0 + 8] = t1;
}

// ---- level-2 gcn epilogue (no relu) fused with column partial sums
__global__ __launch_bounds__(128) void epi_colsum_kernel(const float* __restrict__ G2,
                                                         const float* __restrict__ y2B,
                                                         const float* __restrict__ rs2,
                                                         const float* __restrict__ diag2,
                                                         const float* __restrict__ b2,
                                                         float* __restrict__ part,
                                                         int n2, int rpb) {
  int d = threadIdx.x, b = blockIdx.x;
  float s = 0.f;
  for (int i = 0; i < rpb; ++i)
    s += epi_h(G2, y2B, rs2, diag2, b2, n2, b * rpb + i, d, false);
  part[(size_t)b * 128 + d] = s;
}

__global__ __launch_bounds__(128) void final_kernel(const float* __restrict__ partial, int nb,
                                                    const float* __restrict__ b2,
                                                    const float* __restrict__ Wlin,
                                                    const float* __restrict__ blin,
                                                    float* __restrict__ out) {
  int d = threadIdx.x;
  float cs = 0.f;
  for (int b = 0; b < nb; ++b) cs += partial[(size_t)b * 128 + d];
  // rows >=1024 of h2 are exactly b2 each (zero x2, identity-normalized diag)
  float mean = (cs + 1024.f * b2[d]) * (1.f / 2048.f);
  __shared__ float r0[128], r1[128];
  r0[d] = mean * Wlin[d];
  r1[d] = mean * Wlin[128 + d];
  __syncthreads();
  for (int s = 64; s > 0; s >>= 1) {
    if (d < s) { r0[d] += r0[d + s]; r1[d] += r1[d + s]; }
    __syncthreads();
  }
  if (d == 0) {
    float z0 = fmaxf(r0[0] + blin[0], 0.f);
    float z1 = fmaxf(r1[0] + blin[1], 0.f);
    float mz = fmaxf(z0, z1);
    float lse = mz + logf(__expf(z0 - mz) + __expf(z1 - mz));
    out[0] = z0 - lse;
    out[1] = z1 - lse;
  }
}

extern "C" void kernel_launch(void* const* d_in, const int* in_sizes, int n_in,
                              void* d_out, int out_size, void* d_ws, size_t ws_size,
                              hipStream_t stream) {
  const float* x      = (const float*)d_in[0];
  const float* eidx   = (const float*)d_in[1];
  const float* newadj = eidx + (size_t)4096 * 4096;  // edge_index[1]
  const float* ca1    = (const float*)d_in[3];
  const float* W1     = (const float*)d_in[4];
  const float* b1     = (const float*)d_in[5];
  const float* W2     = (const float*)d_in[6];
  const float* b2     = (const float*)d_in[7];
  const float* Wlin   = (const float*)d_in[8];
  const float* blin   = (const float*)d_in[9];
  float* out = (float*)d_out;

  if (ws_size < 40u * 1024u * 1024u) return;

  char* p = (char*)d_ws;
  auto alloc = [&](size_t bytes) -> char* {
    char* r = p; p += (bytes + 255) & ~(size_t)255; return r;
  };
  unsigned short* adj1h = (unsigned short*)alloc((size_t)2048 * 2048 * 2);
  float* d1raw = (float*)alloc(2048 * 4);
  float* diag1 = (float*)alloc(2048 * 4);
  float* x1b   = (float*)alloc((size_t)2048 * 128 * 4);
  unsigned short* QhB = (unsigned short*)alloc((size_t)2048 * 128 * 2);
  unsigned short* QlB = (unsigned short*)alloc((size_t)2048 * 128 * 2);
  unsigned short* KhB = (unsigned short*)alloc((size_t)4096 * 128 * 2);
  unsigned short* KlB = (unsigned short*)alloc((size_t)4096 * 128 * 2);
  unsigned short* VTB = (unsigned short*)alloc((size_t)4096 * 128 * 2);
  float* pmB   = (float*)alloc((size_t)2048 * 16 * 4);
  float* plB   = (float*)alloc((size_t)2048 * 16 * 4);
  unsigned short* pacc = (unsigned short*)alloc((size_t)2048 * 16 * 128 * 2);
  float* yB    = (float*)alloc((size_t)2048 * 128 * 4);
  unsigned short* yT = (unsigned short*)alloc((size_t)2048 * 128 * 2);
  float* G     = (float*)alloc((size_t)2 * 2048 * 128 * 4);
  unsigned short* adj2h = (unsigned short*)alloc((size_t)1024 * 1024 * 2);
  float* d2raw = (float*)alloc(1024 * 4);
  float* diag2 = (float*)alloc(1024 * 4);
  float* y2B   = (float*)alloc((size_t)1024 * 128 * 4);
  unsigned short* y2T = (unsigned short*)alloc((size_t)1024 * 128 * 2);
  float* G2    = (float*)alloc((size_t)2 * 1024 * 128 * 4);
  float* part  = (float*)alloc((size_t)8 * 128 * 4);

  // 1. adj1 (bf16) + rowsums + diag
  pool_adj_rs_kernel<float><<<256, 256, 0, stream>>>(newadj, adj1h, d1raw, diag1, 2048, 4096);
  // 2. K hi/lo + V^T from x
  split_transpose_kernel<<<dim3(4096 / 32, 4), 256, 0, stream>>>(x, KhB, KlB, VTB, 4096);
  // 3. x1b = row-pool(x); Q = x1b @ ca1 (hi/lo)
  gemm_q_kernel<<<2048 / 16, 128, 0, stream>>>(x, ca1, x1b, QhB, QlB);
  // 4. flash attention partials
  flash_kernel<<<2048, 64, 0, stream>>>(QhB, QlB, KhB, KlB, VTB, pacc, pmB, plB);
  // 5. combine -> x1 (LDS); y = d1 .* (x1 @ W1); yT
  combine_gemm_kernel<<<2048 / 16, 128, 0, stream>>>(pacc, pmB, plB, x1b, W1, d1raw, diag1, yB, yT, 2048);
  // 6. G (2 partials) = adj1h @ y
  mfma_gemm_kernel<<<dim3(2048 / 16, 8, 2), 64, 0, stream>>>(adj1h, yT, G, 2048, 2048);
  // 7. adj2 (bf16) + rowsums + diag
  pool_adj_rs_kernel<unsigned short><<<128, 256, 0, stream>>>(adj1h, adj2h, d2raw, diag2, 1024, 2048);
  // 8. h (inline) -> x2 = row-pool(h) (LDS); y2 = d2 .* (x2 @ W2); y2T
  epi_pool_gemm_kernel<<<1024 / 16, 128, 0, stream>>>(G, yB, d1raw, diag1, b1, W2, d2raw, diag2, y2B, y2T, 2048, 1024);
  // 9. G2 (2 partials) = adj2h @ y2
  mfma_gemm_kernel<<<dim3(1024 / 16, 8, 2), 64, 0, stream>>>(adj2h, y2T, G2, 1024, 1024);
  // 10. h2 (inline, no relu) -> column partial sums
  epi_colsum_kernel<<<8, 128, 0, stream>>>(G2, y2B, d2raw, diag2, b2, part, 1024, 128);
  // 11. mean + linear + relu + log_softmax
  final_kernel<<<1, 128, 0, stream>>>(part, 8, b2, Wlin, blin, out);
}

// Round 4
// 218.001 us; speedup vs baseline: 1.1186x; 1.1186x over previous
//
#include <hip/hip_runtime.h>

typedef float  f32x4 __attribute__((ext_vector_type(4)));
typedef float  f32x2 __attribute__((ext_vector_type(2)));
typedef short  short8v __attribute__((ext_vector_type(8)));

static __device__ __forceinline__ unsigned short f2bf(float f) {
  union { float f; unsigned u; } v; v.f = f;
  unsigned r = v.u + 0x7FFFu + ((v.u >> 16) & 1u);   // RNE
  return (unsigned short)(r >> 16);
}
static __device__ __forceinline__ float bf2f(unsigned short h) {
  union { unsigned u; float f; } v; v.u = ((unsigned)h) << 16;
  return v.f;
}
static __device__ __forceinline__ f32x4 mfma16(short8v a, short8v b, f32x4 c) {
  return __builtin_amdgcn_mfma_f32_16x16x32_bf16(a, b, c, 0, 0, 0);
}

// ---- window-of-4 loaders (c0 even, no wrap) ----
static __device__ __forceinline__ float win4(const float* row, int c0) {
  f32x2 u = *(const f32x2*)(row + c0);
  f32x2 w = *(const f32x2*)(row + c0 + 2);
  return u[0] + u[1] + w[0] + w[1];
}
static __device__ __forceinline__ float win4(const unsigned short* row, int c0) {
  unsigned a = *(const unsigned*)(row + c0);
  unsigned b = *(const unsigned*)(row + c0 + 2);
  return bf2f((unsigned short)a) + bf2f((unsigned short)(a >> 16)) +
         bf2f((unsigned short)b) + bf2f((unsigned short)(b >> 16));
}
static __device__ __forceinline__ float elt(const float* r, int c) { return r[c]; }
static __device__ __forceinline__ float elt(const unsigned short* r, int c) { return bf2f(r[c]); }

// ---- fused adj pooling + rowsum + diag extract.
// out[j,k] = sum_{a,b in 0..3} in[(2j+a)%nin][(2k+b)%nin] (bf16)
// rs[j] = f32 rowsum of out row j; diag[j] = f32 out[j,j].
// One output row per block (8 blocks/CU); XCD-swizzled so adjacent rows
// (which share 2 of 4 input rows) run on the same XCD -> overlap L2-hits.
template <typename T>
__global__ __launch_bounds__(256) void pool_adj_rs_kernel(const T* __restrict__ in,
                                                          unsigned short* __restrict__ outh,
                                                          float* __restrict__ rs,
                                                          float* __restrict__ diag,
                                                          int n, int nin) {
  int chunk = n >> 3;                       // n % 8 == 0 -> bijective swizzle
  int bid = blockIdx.x;
  int j = (bid & 7) * chunk + (bid >> 3);
  int r0 = 2 * j;
  const T* row0 = in + (size_t)((r0 + 0) & (nin - 1)) * nin;
  const T* row1 = in + (size_t)((r0 + 1) & (nin - 1)) * nin;
  const T* row2 = in + (size_t)((r0 + 2) & (nin - 1)) * nin;
  const T* row3 = in + (size_t)((r0 + 3) & (nin - 1)) * nin;
  float racc = 0.f;
  for (int k = threadIdx.x; k < n; k += 256) {
    int c0 = 2 * k;
    float s;
    if (c0 + 3 < nin) {
      s = win4(row0, c0) + win4(row1, c0) + win4(row2, c0) + win4(row3, c0);
    } else {
      s = 0.f;
      #pragma unroll
      for (int b = 0; b < 4; ++b) {
        int c = (c0 + b) & (nin - 1);
        s += elt(row0, c) + elt(row1, c) + elt(row2, c) + elt(row3, c);
      }
    }
    outh[(size_t)j * n + k] = f2bf(s);
    racc += s;
    if (k == j) diag[j] = s;               // exactly one thread owns k==j
  }
  #pragma unroll
  for (int o = 32; o > 0; o >>= 1) racc += __shfl_xor(racc, o);
  __shared__ float red[4];
  if ((threadIdx.x & 63) == 0) red[threadIdx.x >> 6] = racc;
  __syncthreads();
  if (threadIdx.x == 0) rs[j] = red[0] + red[1] + red[2] + red[3];
}

// ---- emit bf16 hi/lo of X and transposed bf16 hi (for K and V^T)
__global__ __launch_bounds__(256) void split_transpose_kernel(const float* __restrict__ X,
                                                              unsigned short* __restrict__ Oh,
                                                              unsigned short* __restrict__ Ol,
                                                              unsigned short* __restrict__ OT,
                                                              int M) {
  __shared__ unsigned short t[32][33];
  int i0 = blockIdx.x * 32, d0 = blockIdx.y * 32;
  int tx = threadIdx.x & 31, ty = threadIdx.x >> 5;
  #pragma unroll
  for (int rr = 0; rr < 4; ++rr) {
    int i = i0 + ty + rr * 8;
    int d = d0 + tx;
    float v = X[(size_t)i * 128 + d];
    unsigned short hi = f2bf(v);
    Oh[(size_t)i * 128 + d] = hi;
    Ol[(size_t)i * 128 + d] = f2bf(v - bf2f(hi));
    t[ty + rr * 8][tx] = hi;
  }
  __syncthreads();
  #pragma unroll
  for (int rr = 0; rr < 4; ++rr) {
    int d = d0 + ty + rr * 8;
    int i = i0 + tx;
    OT[(size_t)d * M + i] = t[tx][ty + rr * 8];
  }
}

// ---- shared 16x128 @ 128x128 gemm body (xs in LDS, thread owns col d)
static __device__ __forceinline__ void gemm16x128(const float (*xs)[128],
                                                  const float* __restrict__ W,
                                                  int d, float* acc) {
  #pragma unroll
  for (int i = 0; i < 16; ++i) acc[i] = 0.f;
  for (int e = 0; e < 128; e += 4) {
    float w0 = W[(e + 0) * 128 + d];
    float w1 = W[(e + 1) * 128 + d];
    float w2 = W[(e + 2) * 128 + d];
    float w3 = W[(e + 3) * 128 + d];
    #pragma unroll
    for (int i = 0; i < 16; ++i) {
      f32x4 xv = *(const f32x4*)&xs[i][e];
      float a = acc[i];
      a = fmaf(xv[0], w0, a);
      a = fmaf(xv[1], w1, a);
      a = fmaf(xv[2], w2, a);
      a = fmaf(xv[3], w3, a);
      acc[i] = a;
    }
  }
}

// ---- x1b = row-pool(x); Q = x1b @ ca1 split to bf16 hi/lo
__global__ __launch_bounds__(128) void gemm_q_kernel(const float* __restrict__ x,
                                                     const float* __restrict__ W,
                                                     float* __restrict__ x1b,
                                                     unsigned short* __restrict__ Qh,
                                                     unsigned short* __restrict__ Ql) {
  __shared__ float xs[16][128];
  int r0 = blockIdx.x * 16;
  int d = threadIdx.x;
  #pragma unroll
  for (int i = 0; i < 16; ++i) {
    int rr = 2 * (r0 + i);
    float v = x[(size_t)((rr + 0) & 4095) * 128 + d] + x[(size_t)((rr + 1) & 4095) * 128 + d] +
              x[(size_t)((rr + 2) & 4095) * 128 + d] + x[(size_t)((rr + 3) & 4095) * 128 + d];
    xs[i][d] = v;
    x1b[(size_t)(r0 + i) * 128 + d] = v;
  }
  __syncthreads();
  float acc[16];
  gemm16x128(xs, W, d, acc);
  #pragma unroll
  for (int i = 0; i < 16; ++i) {
    size_t o = (size_t)(r0 + i) * 128 + d;
    unsigned short hi = f2bf(acc[i]);
    Qh[o] = hi;
    Ql[o] = f2bf(acc[i] - bf2f(hi));
  }
}

// ---- split-K flash attention partials (bf16x3 QK^T, masked-to-zero scores).
// Block (jt,kc): q-rows jt*16..+15 over k-range kc*256..+255, 1 wave.
// S computed transposed (A=K tile, B=Q^T) so lane owns q = lane&15.
__global__ __launch_bounds__(64) void flash_kernel(const unsigned short* __restrict__ Qh,
                                                   const unsigned short* __restrict__ Ql,
                                                   const unsigned short* __restrict__ Kh,
                                                   const unsigned short* __restrict__ Kl,
                                                   const unsigned short* __restrict__ VT,
                                                   unsigned short* __restrict__ pacc,
                                                   float* __restrict__ pm,
                                                   float* __restrict__ pl) {
  int bid = blockIdx.x;
  int jt = bid >> 4, kc = bid & 15;
  int lane = threadIdx.x;
  int q = lane & 15, g = lane >> 4;
  int j = jt * 16 + q;
  int kbase = kc * 256;
  int twoj = 2 * j;
  __shared__ unsigned short P[16][32];

  short8v qh[4], ql[4];
  #pragma unroll
  for (int c = 0; c < 4; ++c) {
    qh[c] = *(const short8v*)&Qh[(size_t)j * 128 + c * 32 + g * 8];
    ql[c] = *(const short8v*)&Ql[(size_t)j * 128 + c * 32 + g * 8];
  }
  float m = -1e30f, l = 0.f;
  f32x4 acc[8];
  #pragma unroll
  for (int t = 0; t < 8; ++t) acc[t] = (f32x4){0.f, 0.f, 0.f, 0.f};

  for (int step = 0; step < 8; ++step) {
    int kt = kbase + step * 32;
    const unsigned short* ka_h = Kh + (size_t)(kt + q) * 128;
    const unsigned short* ka_l = Kl + (size_t)(kt + q) * 128;
    const unsigned short* kb_h = ka_h + 16 * 128;
    const unsigned short* kb_l = ka_l + 16 * 128;
    f32x4 z = {0.f, 0.f, 0.f, 0.f};
    f32x4 hh0 = z, hl0 = z, lh0 = z, hh1 = z, hl1 = z, lh1 = z;
    __builtin_amdgcn_s_setprio(1);
    #pragma unroll
    for (int c = 0; c < 4; ++c) {
      int off = c * 32 + g * 8;
      short8v ah = *(const short8v*)(ka_h + off);
      short8v al = *(const short8v*)(ka_l + off);
      short8v bh = *(const short8v*)(kb_h + off);
      short8v bl = *(const short8v*)(kb_l + off);
      hh0 = mfma16(ah, qh[c], hh0);   // 6 independent 4-deep chains
      hh1 = mfma16(bh, qh[c], hh1);
      hl0 = mfma16(ah, ql[c], hl0);
      hl1 = mfma16(bh, ql[c], hl1);
      lh0 = mfma16(al, qh[c], lh0);
      lh1 = mfma16(bl, qh[c], lh1);
    }
    __builtin_amdgcn_s_setprio(0);
    // prefetch V fragments now: consumed only after softmax, hides L2 latency
    short8v vfrag[8];
    const unsigned short* vb = VT + kt + g * 8;
    #pragma unroll
    for (int t = 0; t < 8; ++t)
      vfrag[t] = *(const short8v*)(vb + (size_t)(t * 16 + q) * 4096);

    f32x4 s0 = hh0 + hl0 + lh0;
    f32x4 s1 = hh1 + hl1 + lh1;
    float sv[8];
    #pragma unroll
    for (int r = 0; r < 4; ++r) {
      int k0 = kt + g * 4 + r;          // D row = k-within-tile = 4g+r
      float v0 = s0[r];
      if (((k0 - twoj) & 4095) < 4) v0 = 0.f;
      sv[r] = v0;
      int k1 = k0 + 16;
      float v1 = s1[r];
      if (((k1 - twoj) & 4095) < 4) v1 = 0.f;
      sv[4 + r] = v1;
    }
    float cmx = sv[0];
    #pragma unroll
    for (int r = 1; r < 8; ++r) cmx = fmaxf(cmx, sv[r]);
    cmx = fmaxf(cmx, __shfl_xor(cmx, 16));
    cmx = fmaxf(cmx, __shfl_xor(cmx, 32));
    float mnew = fmaxf(m, cmx);
    float ps = 0.f;
    unsigned short pb[8];
    #pragma unroll
    for (int r = 0; r < 8; ++r) {
      float pv = __expf(sv[r] - mnew);
      ps += pv;
      pb[r] = f2bf(pv);
    }
    ps += __shfl_xor(ps, 16);
    ps += __shfl_xor(ps, 32);
    if (__any(cmx > m)) {               // defer-rescale: skip when max didn't grow
      float scl = __expf(m - mnew);
      l *= scl;
      float sc0 = __shfl(scl, 4 * g + 0);
      float sc1 = __shfl(scl, 4 * g + 1);
      float sc2 = __shfl(scl, 4 * g + 2);
      float sc3 = __shfl(scl, 4 * g + 3);
      #pragma unroll
      for (int t = 0; t < 8; ++t) {
        acc[t][0] *= sc0; acc[t][1] *= sc1; acc[t][2] *= sc2; acc[t][3] *= sc3;
      }
    }
    m = mnew;
    l += ps;
    // write P[q][k_local]: tile a k_local=4g+r, tile b 16+4g+r (packed pairs)
    *(unsigned*)&P[q][4 * g]          = (unsigned)pb[0] | ((unsigned)pb[1] << 16);
    *(unsigned*)&P[q][4 * g + 2]      = (unsigned)pb[2] | ((unsigned)pb[3] << 16);
    *(unsigned*)&P[q][16 + 4 * g]     = (unsigned)pb[4] | ((unsigned)pb[5] << 16);
    *(unsigned*)&P[q][16 + 4 * g + 2] = (unsigned)pb[6] | ((unsigned)pb[7] << 16);
    __syncthreads();
    short8v pa = *(const short8v*)&P[q][8 * g];   // A-frag: row q, k=8g+e
    __builtin_amdgcn_s_setprio(1);
    #pragma unroll
    for (int t = 0; t < 8; ++t) acc[t] = mfma16(pa, vfrag[t], acc[t]);
    __builtin_amdgcn_s_setprio(0);
    __syncthreads();
  }
  #pragma unroll
  for (int t = 0; t < 8; ++t) {
    #pragma unroll
    for (int r = 0; r < 4; ++r)
      pacc[((size_t)(jt * 16 + g * 4 + r) * 16 + kc) * 128 + t * 16 + q] = f2bf(acc[t][r]);
  }
  if (g == 0) {
    pm[(size_t)j * 16 + kc] = m;
    pl[(size_t)j * 16 + kc] = l;
  }
}

// ---- merge split-K partials -> x1 = alpha@x + x1b (LDS); y = d1.*(x1@W1); yT bf16
__global__ __launch_bounds__(128) void combine_gemm_kernel(const unsigned short* __restrict__ pacc,
                                                           const float* __restrict__ pm,
                                                           const float* __restrict__ pl,
                                                           const float* __restrict__ x1b,
                                                           const float* __restrict__ W,
                                                           const float* __restrict__ rs,
                                                           const float* __restrict__ diag,
                                                           float* __restrict__ yB,
                                                           unsigned short* __restrict__ YT,
                                                           int M) {
  __shared__ float xs[16][128];
  int r0 = blockIdx.x * 16;
  int d = threadIdx.x;
  #pragma unroll
  for (int i = 0; i < 16; ++i) {
    int j = r0 + i;
    float Mx = -1e30f;
    #pragma unroll
    for (int c = 0; c < 16; ++c) Mx = fmaxf(Mx, pm[(size_t)j * 16 + c]);
    float L = 0.f, o = 0.f;
    for (int c = 0; c < 16; ++c) {
      float w = __expf(pm[(size_t)j * 16 + c] - Mx);
      L += pl[(size_t)j * 16 + c] * w;
      o += w * bf2f(pacc[((size_t)j * 16 + c) * 128 + d]);
    }
    xs[i][d] = o / L + x1b[(size_t)j * 128 + d];
  }
  __syncthreads();
  float acc[16];
  gemm16x128(xs, W, d, acc);
  short8v t0, t1;
  #pragma unroll
  for (int i = 0; i < 16; ++i) {
    int j = r0 + i;
    float dv = rsqrtf(fmaxf(rs[j] - diag[j] + 1.f, 1.f));
    float v = acc[i] * dv;
    yB[(size_t)j * 128 + d] = v;
    if (i < 8) t0[i] = (short)f2bf(v); else t1[i - 8] = (short)f2bf(v);
  }
  *(short8v*)&YT[(size_t)d * M + r0] = t0;
  *(short8v*)&YT[(size_t)d * M + r0 + 8] = t1;
}

// ---- C_ks[M,128] partial = A_bf16[M, K-half] @ B, B transposed bf16 BT[128,K]
__global__ __launch_bounds__(64) void mfma_gemm_kernel(const unsigned short* __restrict__ A,
                                                       const unsigned short* __restrict__ BT,
                                                       float* __restrict__ C, int K, int M) {
  int jt = blockIdx.x, nt = blockIdx.y, ks = blockIdx.z;
  int lane = threadIdx.x;
  int q = lane & 15, g = lane >> 4;
  const unsigned short* arow = A + (size_t)(jt * 16 + q) * K;
  const unsigned short* brow = BT + (size_t)(nt * 16 + q) * K;
  int kbeg = ks * (K >> 1), kend = kbeg + (K >> 1);
  f32x4 acc = {0.f, 0.f, 0.f, 0.f};
  for (int k0 = kbeg; k0 < kend; k0 += 32) {
    int ka = k0 + g * 8;
    short8v af = *(const short8v*)(arow + ka);
    short8v bf = *(const short8v*)(brow + ka);
    acc = mfma16(af, bf, acc);
  }
  float* Cp = C + (size_t)ks * M * 128;
  #pragma unroll
  for (int r = 0; r < 4; ++r)
    Cp[(size_t)(jt * 16 + g * 4 + r) * 128 + nt * 16 + q] = acc[r];
}

// ---- GCN epilogue element: h[r][d] (G = 2 K-split partials, n rows each)
static __device__ __forceinline__ float epi_h(const float* __restrict__ G,
                                              const float* __restrict__ y,
                                              const float* __restrict__ rs,
                                              const float* __restrict__ diag,
                                              const float* __restrict__ bias,
                                              int n, int r, int d, bool relu) {
  float dv = rsqrtf(fmaxf(rs[r] - diag[r] + 1.f, 1.f));
  float gs = G[(size_t)r * 128 + d] + G[(size_t)(n + r) * 128 + d];
  float v = dv * (gs + (1.f - diag[r]) * y[(size_t)r * 128 + d]) + bias[d];
  return relu ? fmaxf(v, 0.f) : v;
}

// ---- x2 = row-pool(relu-gcn-epi(level1)); y2 = d2.*(x2@W2); y2T bf16
__global__ __launch_bounds__(128) void epi_pool_gemm_kernel(const float* __restrict__ G,
                                                            const float* __restrict__ yB,
                                                            const float* __restrict__ rs1,
                                                            const float* __restrict__ diag1,
                                                            const float* __restrict__ b1,
                                                            const float* __restrict__ W,
                                                            const float* __restrict__ rs2,
                                                            const float* __restrict__ diag2,
                                                            float* __restrict__ y2B,
                                                            unsigned short* __restrict__ Y2T,
                                                            int n1, int M2) {
  __shared__ float xs[16][128];
  int r0 = blockIdx.x * 16;
  int d = threadIdx.x;
  #pragma unroll
  for (int i = 0; i < 16; ++i) {
    int rr = 2 * (r0 + i);
    float s = 0.f;
    #pragma unroll
    for (int a = 0; a < 4; ++a)
      s += epi_h(G, yB, rs1, diag1, b1, n1, (rr + a) & (n1 - 1), d, true);
    xs[i][d] = s;
  }
  __syncthreads();
  float acc[16];
  gemm16x128(xs, W, d, acc);
  short8v t0, t1;
  #pragma unroll
  for (int i = 0; i < 16; ++i) {
    int j = r0 + i;
    float dv = rsqrtf(fmaxf(rs2[j] - diag2[j] + 1.f, 1.f));
    float v = acc[i] * dv;
    y2B[(size_t)j * 128 + d] = v;
    if (i < 8) t0[i] = (short)f2bf(v); else t1[i - 8] = (short)f2bf(v);
  }
  *(short8v*)&Y2T[(size_t)d * M2 + r0] = t0;
  *(short8v*)&Y2T[(size_t)d * M2 + r0 + 8] = t1;
}

// ---- level-2 gcn epilogue (no relu) fused with column partial sums
__global__ __launch_bounds__(128) void epi_colsum_kernel(const float* __restrict__ G2,
                                                         const float* __restrict__ y2B,
                                                         const float* __restrict__ rs2,
                                                         const float* __restrict__ diag2,
                                                         const float* __restrict__ b2,
                                                         float* __restrict__ part,
                                                         int n2, int rpb) {
  int d = threadIdx.x, b = blockIdx.x;
  float s = 0.f;
  for (int i = 0; i < rpb; ++i)
    s += epi_h(G2, y2B, rs2, diag2, b2, n2, b * rpb + i, d, false);
  part[(size_t)b * 128 + d] = s;
}

__global__ __launch_bounds__(128) void final_kernel(const float* __restrict__ partial, int nb,
                                                    const float* __restrict__ b2,
                                                    const float* __restrict__ Wlin,
                                                    const float* __restrict__ blin,
                                                    float* __restrict__ out) {
  int d = threadIdx.x;
  float cs = 0.f;
  for (int b = 0; b < nb; ++b) cs += partial[(size_t)b * 128 + d];
  // rows >=1024 of h2 are exactly b2 each (zero x2, identity-normalized diag)
  float mean = (cs + 1024.f * b2[d]) * (1.f / 2048.f);
  __shared__ float r0[128], r1[128];
  r0[d] = mean * Wlin[d];
  r1[d] = mean * Wlin[128 + d];
  __syncthreads();
  for (int s = 64; s > 0; s >>= 1) {
    if (d < s) { r0[d] += r0[d + s]; r1[d] += r1[d + s]; }
    __syncthreads();
  }
  if (d == 0) {
    float z0 = fmaxf(r0[0] + blin[0], 0.f);
    float z1 = fmaxf(r1[0] + blin[1], 0.f);
    float mz = fmaxf(z0, z1);
    float lse = mz + logf(__expf(z0 - mz) + __expf(z1 - mz));
    out[0] = z0 - lse;
    out[1] = z1 - lse;
  }
}

extern "C" void kernel_launch(void* const* d_in, const int* in_sizes, int n_in,
                              void* d_out, int out_size, void* d_ws, size_t ws_size,
                              hipStream_t stream) {
  const float* x      = (const float*)d_in[0];
  const float* eidx   = (const float*)d_in[1];
  const float* newadj = eidx + (size_t)4096 * 4096;  // edge_index[1]
  const float* ca1    = (const float*)d_in[3];
  const float* W1     = (const float*)d_in[4];
  const float* b1     = (const float*)d_in[5];
  const float* W2     = (const float*)d_in[6];
  const float* b2     = (const float*)d_in[7];
  const float* Wlin   = (const float*)d_in[8];
  const float* blin   = (const float*)d_in[9];
  float* out = (float*)d_out;

  if (ws_size < 40u * 1024u * 1024u) return;

  char* p = (char*)d_ws;
  auto alloc = [&](size_t bytes) -> char* {
    char* r = p; p += (bytes + 255) & ~(size_t)255; return r;
  };
  unsigned short* adj1h = (unsigned short*)alloc((size_t)2048 * 2048 * 2);
  float* d1raw = (float*)alloc(2048 * 4);
  float* diag1 = (float*)alloc(2048 * 4);
  float* x1b   = (float*)alloc((size_t)2048 * 128 * 4);
  unsigned short* QhB = (unsigned short*)alloc((size_t)2048 * 128 * 2);
  unsigned short* QlB = (unsigned short*)alloc((size_t)2048 * 128 * 2);
  unsigned short* KhB = (unsigned short*)alloc((size_t)4096 * 128 * 2);
  unsigned short* KlB = (unsigned short*)alloc((size_t)4096 * 128 * 2);
  unsigned short* VTB = (unsigned short*)alloc((size_t)4096 * 128 * 2);
  float* pmB   = (float*)alloc((size_t)2048 * 16 * 4);
  float* plB   = (float*)alloc((size_t)2048 * 16 * 4);
  unsigned short* pacc = (unsigned short*)alloc((size_t)2048 * 16 * 128 * 2);
  float* yB    = (float*)alloc((size_t)2048 * 128 * 4);
  unsigned short* yT = (unsigned short*)alloc((size_t)2048 * 128 * 2);
  float* G     = (float*)alloc((size_t)2 * 2048 * 128 * 4);
  unsigned short* adj2h = (unsigned short*)alloc((size_t)1024 * 1024 * 2);
  float* d2raw = (float*)alloc(1024 * 4);
  float* diag2 = (float*)alloc(1024 * 4);
  float* y2B   = (float*)alloc((size_t)1024 * 128 * 4);
  unsigned short* y2T = (unsigned short*)alloc((size_t)1024 * 128 * 2);
  float* G2    = (float*)alloc((size_t)2 * 1024 * 128 * 4);
  float* part  = (float*)alloc((size_t)8 * 128 * 4);

  // 1. adj1 (bf16) + rowsums + diag  (one row per block, XCD-swizzled)
  pool_adj_rs_kernel<float><<<2048, 256, 0, stream>>>(newadj, adj1h, d1raw, diag1, 2048, 4096);
  // 2. K hi/lo + V^T from x
  split_transpose_kernel<<<dim3(4096 / 32, 4), 256, 0, stream>>>(x, KhB, KlB, VTB, 4096);
  // 3. x1b = row-pool(x); Q = x1b @ ca1 (hi/lo)
  gemm_q_kernel<<<2048 / 16, 128, 0, stream>>>(x, ca1, x1b, QhB, QlB);
  // 4. flash attention partials
  flash_kernel<<<2048, 64, 0, stream>>>(QhB, QlB, KhB, KlB, VTB, pacc, pmB, plB);
  // 5. combine -> x1 (LDS); y = d1 .* (x1 @ W1); yT
  combine_gemm_kernel<<<2048 / 16, 128, 0, stream>>>(pacc, pmB, plB, x1b, W1, d1raw, diag1, yB, yT, 2048);
  // 6. G (2 partials) = adj1h @ y
  mfma_gemm_kernel<<<dim3(2048 / 16, 8, 2), 64, 0, stream>>>(adj1h, yT, G, 2048, 2048);
  // 7. adj2 (bf16) + rowsums + diag
  pool_adj_rs_kernel<unsigned short><<<1024, 256, 0, stream>>>(adj1h, adj2h, d2raw, diag2, 1024, 2048);
  // 8. h (inline) -> x2 = row-pool(h) (LDS); y2 = d2 .* (x2 @ W2); y2T
  epi_pool_gemm_kernel<<<1024 / 16, 128, 0, stream>>>(G, yB, d1raw, diag1, b1, W2, d2raw, diag2, y2B, y2T, 2048, 1024);
  // 9. G2 (2 partials) = adj2h @ y2
  mfma_gemm_kernel<<<dim3(1024 / 16, 8, 2), 64, 0, stream>>>(adj2h, y2T, G2, 1024, 1024);
  // 10. h2 (inline, no relu) -> column partial sums
  epi_colsum_kernel<<<8, 128, 0, stream>>>(G2, y2B, d2raw, diag2, b2, part, 1024, 128);
  // 11. mean + linear + relu + log_softmax
  final_kernel<<<1, 128, 0, stream>>>(part, 8, b2, Wlin, blin, out);
}

// Round 5
// 190.605 us; speedup vs baseline: 1.2793x; 1.1437x over previous
//
#include <hip/hip_runtime.h>

typedef float  f32x4 __attribute__((ext_vector_type(4)));
typedef float  f32x2 __attribute__((ext_vector_type(2)));
typedef short  short8v __attribute__((ext_vector_type(8)));

static __device__ __forceinline__ unsigned short f2bf(float f) {
  union { float f; unsigned u; } v; v.f = f;
  unsigned r = v.u + 0x7FFFu + ((v.u >> 16) & 1u);   // RNE
  return (unsigned short)(r >> 16);
}
static __device__ __forceinline__ float bf2f(unsigned short h) {
  union { unsigned u; float f; } v; v.u = ((unsigned)h) << 16;
  return v.f;
}
static __device__ __forceinline__ f32x4 mfma16(short8v a, short8v b, f32x4 c) {
  return __builtin_amdgcn_mfma_f32_16x16x32_bf16(a, b, c, 0, 0, 0);
}

// ---- window-of-4 loaders (c0 even, no wrap) ----
static __device__ __forceinline__ float win4(const float* row, int c0) {
  f32x2 u = *(const f32x2*)(row + c0);
  f32x2 w = *(const f32x2*)(row + c0 + 2);
  return u[0] + u[1] + w[0] + w[1];
}
static __device__ __forceinline__ float win4(const unsigned short* row, int c0) {
  unsigned a = *(const unsigned*)(row + c0);
  unsigned b = *(const unsigned*)(row + c0 + 2);
  return bf2f((unsigned short)a) + bf2f((unsigned short)(a >> 16)) +
         bf2f((unsigned short)b) + bf2f((unsigned short)(b >> 16));
}
static __device__ __forceinline__ float elt(const float* r, int c) { return r[c]; }
static __device__ __forceinline__ float elt(const unsigned short* r, int c) { return bf2f(r[c]); }

// ---- adj pooling body: out[j,k] = sum_{a,b in 0..3} in[(2j+a)%nin][(2k+b)%nin] (bf16)
// + f32 rowsum + diag. One output row per call (256 threads). XCD-swizzled j.
template <typename T>
static __device__ void pool_adj_body(const T* __restrict__ in,
                                     unsigned short* __restrict__ outh,
                                     float* __restrict__ rs,
                                     float* __restrict__ diag,
                                     int n, int nin, int bid, float* red) {
  int chunk = n >> 3;                       // n % 8 == 0 -> bijective swizzle
  int j = (bid & 7) * chunk + (bid >> 3);
  int r0 = 2 * j;
  const T* row0 = in + (size_t)((r0 + 0) & (nin - 1)) * nin;
  const T* row1 = in + (size_t)((r0 + 1) & (nin - 1)) * nin;
  const T* row2 = in + (size_t)((r0 + 2) & (nin - 1)) * nin;
  const T* row3 = in + (size_t)((r0 + 3) & (nin - 1)) * nin;
  float racc = 0.f;
  for (int k = threadIdx.x; k < n; k += 256) {
    int c0 = 2 * k;
    float s;
    if (c0 + 3 < nin) {
      s = win4(row0, c0) + win4(row1, c0) + win4(row2, c0) + win4(row3, c0);
    } else {
      s = 0.f;
      #pragma unroll
      for (int b = 0; b < 4; ++b) {
        int c = (c0 + b) & (nin - 1);
        s += elt(row0, c) + elt(row1, c) + elt(row2, c) + elt(row3, c);
      }
    }
    outh[(size_t)j * n + k] = f2bf(s);
    racc += s;
    if (k == j) diag[j] = s;               // exactly one thread owns k==j
  }
  #pragma unroll
  for (int o = 32; o > 0; o >>= 1) racc += __shfl_xor(racc, o);
  if ((threadIdx.x & 63) == 0) red[threadIdx.x >> 6] = racc;
  __syncthreads();
  if (threadIdx.x == 0) rs[j] = red[0] + red[1] + red[2] + red[3];
}

// ---- bf16 hi/lo split of X + transposed bf16 hi (for K and V^T); 256 threads
static __device__ void split_transpose_body(const float* __restrict__ X,
                                            unsigned short* __restrict__ Oh,
                                            unsigned short* __restrict__ Ol,
                                            unsigned short* __restrict__ OT,
                                            int M, int bb, unsigned short (*t)[33]) {
  int i0 = (bb & 127) * 32, d0 = (bb >> 7) * 32;
  int tx = threadIdx.x & 31, ty = threadIdx.x >> 5;
  #pragma unroll
  for (int rr = 0; rr < 4; ++rr) {
    int i = i0 + ty + rr * 8;
    int d = d0 + tx;
    float v = X[(size_t)i * 128 + d];
    unsigned short hi = f2bf(v);
    Oh[(size_t)i * 128 + d] = hi;
    Ol[(size_t)i * 128 + d] = f2bf(v - bf2f(hi));
    t[ty + rr * 8][tx] = hi;
  }
  __syncthreads();
  #pragma unroll
  for (int rr = 0; rr < 4; ++rr) {
    int d = d0 + ty + rr * 8;
    int i = i0 + tx;
    OT[(size_t)d * M + i] = t[tx][ty + rr * 8];
  }
}

// ---- shared 16x128 @ 128x128 gemm body (xs in LDS, thread owns col d)
static __device__ __forceinline__ void gemm16x128(const float (*xs)[128],
                                                  const float* __restrict__ W,
                                                  int d, float* acc) {
  #pragma unroll
  for (int i = 0; i < 16; ++i) acc[i] = 0.f;
  for (int e = 0; e < 128; e += 4) {
    float w0 = W[(e + 0) * 128 + d];
    float w1 = W[(e + 1) * 128 + d];
    float w2 = W[(e + 2) * 128 + d];
    float w3 = W[(e + 3) * 128 + d];
    #pragma unroll
    for (int i = 0; i < 16; ++i) {
      f32x4 xv = *(const f32x4*)&xs[i][e];
      float a = acc[i];
      a = fmaf(xv[0], w0, a);
      a = fmaf(xv[1], w1, a);
      a = fmaf(xv[2], w2, a);
      a = fmaf(xv[3], w3, a);
      acc[i] = a;
    }
  }
}

// ---- x1b = row-pool(x); Q = x1b @ ca1 (hi/lo).  128 threads per tile.
static __device__ void gemm_q_body(const float* __restrict__ x,
                                   const float* __restrict__ W,
                                   float* __restrict__ x1b,
                                   unsigned short* __restrict__ Qh,
                                   unsigned short* __restrict__ Ql,
                                   int tile, float (*xs)[128], int d) {
  int r0 = tile * 16;
  #pragma unroll
  for (int i = 0; i < 16; ++i) {
    int rr = 2 * (r0 + i);
    float v = x[(size_t)((rr + 0) & 4095) * 128 + d] + x[(size_t)((rr + 1) & 4095) * 128 + d] +
              x[(size_t)((rr + 2) & 4095) * 128 + d] + x[(size_t)((rr + 3) & 4095) * 128 + d];
    xs[i][d] = v;
    x1b[(size_t)(r0 + i) * 128 + d] = v;
  }
  __syncthreads();
  float acc[16];
  gemm16x128(xs, W, d, acc);
  #pragma unroll
  for (int i = 0; i < 16; ++i) {
    size_t o = (size_t)(r0 + i) * 128 + d;
    unsigned short hi = f2bf(acc[i]);
    Qh[o] = hi;
    Ql[o] = f2bf(acc[i] - bf2f(hi));
  }
}

// ---- mega1: pool_adj(level1) || split_transpose || gemm_q
__global__ __launch_bounds__(256) void mega1_kernel(const float* __restrict__ newadj,
                                                    unsigned short* __restrict__ adj1h,
                                                    float* __restrict__ rs1,
                                                    float* __restrict__ diag1,
                                                    const float* __restrict__ x,
                                                    unsigned short* __restrict__ Kh,
                                                    unsigned short* __restrict__ Kl,
                                                    unsigned short* __restrict__ VT,
                                                    const float* __restrict__ ca1,
                                                    float* __restrict__ x1b,
                                                    unsigned short* __restrict__ Qh,
                                                    unsigned short* __restrict__ Ql) {
  __shared__ __align__(16) char smem[16384];
  int b = blockIdx.x;
  if (b < 2048) {
    pool_adj_body<float>(newadj, adj1h, rs1, diag1, 2048, 4096, b, (float*)smem);
  } else if (b < 2560) {
    split_transpose_body(x, Kh, Kl, VT, 4096, b - 2048, (unsigned short (*)[33])smem);
  } else {
    int half = threadIdx.x >> 7, d = threadIdx.x & 127;
    float (*xs)[128] = (float (*)[128])(smem + half * 8192);
    gemm_q_body(x, ca1, x1b, Qh, Ql, (b - 2560) * 2 + half, xs, d);
  }
}

// ---- split-K flash attention partials (bf16x3 QK^T, masked-to-zero scores).
// Block (jt,kc): q-rows jt*16..+15 over k-range kc*256..+255, 1 wave.
// S computed transposed (A=K tile, B=Q^T) so lane owns q = lane&15.
__global__ __launch_bounds__(64) void flash_kernel(const unsigned short* __restrict__ Qh,
                                                   const unsigned short* __restrict__ Ql,
                                                   const unsigned short* __restrict__ Kh,
                                                   const unsigned short* __restrict__ Kl,
                                                   const unsigned short* __restrict__ VT,
                                                   unsigned short* __restrict__ pacc,
                                                   float* __restrict__ pm,
                                                   float* __restrict__ pl) {
  int bid = blockIdx.x;
  int jt = bid >> 4, kc = bid & 15;
  int lane = threadIdx.x;
  int q = lane & 15, g = lane >> 4;
  int j = jt * 16 + q;
  int kbase = kc * 256;
  int twoj = 2 * j;
  __shared__ unsigned short P[16][32];

  short8v qh[4], ql[4];
  #pragma unroll
  for (int c = 0; c < 4; ++c) {
    qh[c] = *(const short8v*)&Qh[(size_t)j * 128 + c * 32 + g * 8];
    ql[c] = *(const short8v*)&Ql[(size_t)j * 128 + c * 32 + g * 8];
  }
  float m = -1e30f, l = 0.f;
  f32x4 acc[8];
  #pragma unroll
  for (int t = 0; t < 8; ++t) acc[t] = (f32x4){0.f, 0.f, 0.f, 0.f};

  for (int step = 0; step < 8; ++step) {
    int kt = kbase + step * 32;
    const unsigned short* ka_h = Kh + (size_t)(kt + q) * 128;
    const unsigned short* ka_l = Kl + (size_t)(kt + q) * 128;
    const unsigned short* kb_h = ka_h + 16 * 128;
    const unsigned short* kb_l = ka_l + 16 * 128;
    f32x4 z = {0.f, 0.f, 0.f, 0.f};
    f32x4 hh0 = z, hl0 = z, lh0 = z, hh1 = z, hl1 = z, lh1 = z;
    __builtin_amdgcn_s_setprio(1);
    #pragma unroll
    for (int c = 0; c < 4; ++c) {
      int off = c * 32 + g * 8;
      short8v ah = *(const short8v*)(ka_h + off);
      short8v al = *(const short8v*)(ka_l + off);
      short8v bh = *(const short8v*)(kb_h + off);
      short8v bl = *(const short8v*)(kb_l + off);
      hh0 = mfma16(ah, qh[c], hh0);   // 6 independent 4-deep chains
      hh1 = mfma16(bh, qh[c], hh1);
      hl0 = mfma16(ah, ql[c], hl0);
      hl1 = mfma16(bh, ql[c], hl1);
      lh0 = mfma16(al, qh[c], lh0);
      lh1 = mfma16(bl, qh[c], lh1);
    }
    __builtin_amdgcn_s_setprio(0);
    // prefetch V fragments now: consumed only after softmax, hides L2 latency
    short8v vfrag[8];
    const unsigned short* vb = VT + kt + g * 8;
    #pragma unroll
    for (int t = 0; t < 8; ++t)
      vfrag[t] = *(const short8v*)(vb + (size_t)(t * 16 + q) * 4096);

    f32x4 s0 = hh0 + hl0 + lh0;
    f32x4 s1 = hh1 + hl1 + lh1;
    float sv[8];
    #pragma unroll
    for (int r = 0; r < 4; ++r) {
      int k0 = kt + g * 4 + r;          // D row = k-within-tile = 4g+r
      float v0 = s0[r];
      if (((k0 - twoj) & 4095) < 4) v0 = 0.f;
      sv[r] = v0;
      int k1 = k0 + 16;
      float v1 = s1[r];
      if (((k1 - twoj) & 4095) < 4) v1 = 0.f;
      sv[4 + r] = v1;
    }
    float cmx = sv[0];
    #pragma unroll
    for (int r = 1; r < 8; ++r) cmx = fmaxf(cmx, sv[r]);
    cmx = fmaxf(cmx, __shfl_xor(cmx, 16));
    cmx = fmaxf(cmx, __shfl_xor(cmx, 32));
    float mnew = fmaxf(m, cmx);
    float ps = 0.f;
    unsigned short pb[8];
    #pragma unroll
    for (int r = 0; r < 8; ++r) {
      float pv = __expf(sv[r] - mnew);
      ps += pv;
      pb[r] = f2bf(pv);
    }
    ps += __shfl_xor(ps, 16);
    ps += __shfl_xor(ps, 32);
    if (__any(cmx > m)) {               // defer-rescale: skip when max didn't grow
      float scl = __expf(m - mnew);
      l *= scl;
      float sc0 = __shfl(scl, 4 * g + 0);
      float sc1 = __shfl(scl, 4 * g + 1);
      float sc2 = __shfl(scl, 4 * g + 2);
      float sc3 = __shfl(scl, 4 * g + 3);
      #pragma unroll
      for (int t = 0; t < 8; ++t) {
        acc[t][0] *= sc0; acc[t][1] *= sc1; acc[t][2] *= sc2; acc[t][3] *= sc3;
      }
    }
    m = mnew;
    l += ps;
    // write P[q][k_local]: tile a k_local=4g+r, tile b 16+4g+r (packed pairs)
    *(unsigned*)&P[q][4 * g]          = (unsigned)pb[0] | ((unsigned)pb[1] << 16);
    *(unsigned*)&P[q][4 * g + 2]      = (unsigned)pb[2] | ((unsigned)pb[3] << 16);
    *(unsigned*)&P[q][16 + 4 * g]     = (unsigned)pb[4] | ((unsigned)pb[5] << 16);
    *(unsigned*)&P[q][16 + 4 * g + 2] = (unsigned)pb[6] | ((unsigned)pb[7] << 16);
    __syncthreads();
    short8v pa = *(const short8v*)&P[q][8 * g];   // A-frag: row q, k=8g+e
    __builtin_amdgcn_s_setprio(1);
    #pragma unroll
    for (int t = 0; t < 8; ++t) acc[t] = mfma16(pa, vfrag[t], acc[t]);
    __builtin_amdgcn_s_setprio(0);
    __syncthreads();
  }
  #pragma unroll
  for (int t = 0; t < 8; ++t) {
    #pragma unroll
    for (int r = 0; r < 4; ++r)
      pacc[((size_t)(jt * 16 + g * 4 + r) * 16 + kc) * 128 + t * 16 + q] = f2bf(acc[t][r]);
  }
  if (g == 0) {
    pm[(size_t)j * 16 + kc] = m;
    pl[(size_t)j * 16 + kc] = l;
  }
}

// ---- merge split-K partials -> x1 = alpha@x + x1b (LDS); y = d1.*(x1@W1); yT bf16
__global__ __launch_bounds__(128) void combine_gemm_kernel(const unsigned short* __restrict__ pacc,
                                                           const float* __restrict__ pm,
                                                           const float* __restrict__ pl,
                                                           const float* __restrict__ x1b,
                                                           const float* __restrict__ W,
                                                           const float* __restrict__ rs,
                                                           const float* __restrict__ diag,
                                                           float* __restrict__ yB,
                                                           unsigned short* __restrict__ YT,
                                                           int M) {
  __shared__ float xs[16][128];
  int r0 = blockIdx.x * 16;
  int d = threadIdx.x;
  #pragma unroll
  for (int i = 0; i < 16; ++i) {
    int j = r0 + i;
    float Mx = -1e30f;
    #pragma unroll
    for (int c = 0; c < 16; ++c) Mx = fmaxf(Mx, pm[(size_t)j * 16 + c]);
    float L = 0.f, o = 0.f;
    for (int c = 0; c < 16; ++c) {
      float w = __expf(pm[(size_t)j * 16 + c] - Mx);
      L += pl[(size_t)j * 16 + c] * w;
      o += w * bf2f(pacc[((size_t)j * 16 + c) * 128 + d]);
    }
    xs[i][d] = o / L + x1b[(size_t)j * 128 + d];
  }
  __syncthreads();
  float acc[16];
  gemm16x128(xs, W, d, acc);
  short8v t0, t1;
  #pragma unroll
  for (int i = 0; i < 16; ++i) {
    int j = r0 + i;
    float dv = rsqrtf(fmaxf(rs[j] - diag[j] + 1.f, 1.f));
    float v = acc[i] * dv;
    yB[(size_t)j * 128 + d] = v;
    if (i < 8) t0[i] = (short)f2bf(v); else t1[i - 8] = (short)f2bf(v);
  }
  *(short8v*)&YT[(size_t)d * M + r0] = t0;
  *(short8v*)&YT[(size_t)d * M + r0 + 8] = t1;
}

// ---- one-wave MFMA tile: C_ks partial = A_bf16 @ BT
static __device__ void mfma_tile_body(const unsigned short* __restrict__ A,
                                      const unsigned short* __restrict__ BT,
                                      float* __restrict__ C, int K, int M,
                                      int jt, int nt, int ks, int lane) {
  int q = lane & 15, g = lane >> 4;
  const unsigned short* arow = A + (size_t)(jt * 16 + q) * K;
  const unsigned short* brow = BT + (size_t)(nt * 16 + q) * K;
  int kbeg = ks * (K >> 1), kend = kbeg + (K >> 1);
  f32x4 acc = {0.f, 0.f, 0.f, 0.f};
  for (int k0 = kbeg; k0 < kend; k0 += 32) {
    int ka = k0 + g * 8;
    short8v af = *(const short8v*)(arow + ka);
    short8v bf = *(const short8v*)(brow + ka);
    acc = mfma16(af, bf, acc);
  }
  float* Cp = C + (size_t)ks * M * 128;
  #pragma unroll
  for (int r = 0; r < 4; ++r)
    Cp[(size_t)(jt * 16 + g * 4 + r) * 128 + nt * 16 + q] = acc[r];
}

// ---- mega2: mfma_gemm(level1, 4 waves/block) || pool_adj(level2)
__global__ __launch_bounds__(256) void mega2_kernel(const unsigned short* __restrict__ adj1h,
                                                    const unsigned short* __restrict__ yT,
                                                    float* __restrict__ G,
                                                    unsigned short* __restrict__ adj2h,
                                                    float* __restrict__ rs2,
                                                    float* __restrict__ diag2) {
  __shared__ float red[4];
  int b = blockIdx.x;
  if (b < 512) {
    int fid = b * 4 + (threadIdx.x >> 6);       // [0,2048)
    int jt = fid & 127, nt = (fid >> 7) & 7, ks = fid >> 10;
    mfma_tile_body(adj1h, yT, G, 2048, 2048, jt, nt, ks, threadIdx.x & 63);
  } else {
    pool_adj_body<unsigned short>(adj1h, adj2h, rs2, diag2, 1024, 2048, b - 512, red);
  }
}

// ---- GCN epilogue element: h[r][d] (G = 2 K-split partials, n rows each)
static __device__ __forceinline__ float epi_h(const float* __restrict__ G,
                                              const float* __restrict__ y,
                                              const float* __restrict__ rs,
                                              const float* __restrict__ diag,
                                              const float* __restrict__ bias,
                                              int n, int r, int d, bool relu) {
  float dv = rsqrtf(fmaxf(rs[r] - diag[r] + 1.f, 1.f));
  float gs = G[(size_t)r * 128 + d] + G[(size_t)(n + r) * 128 + d];
  float v = dv * (gs + (1.f - diag[r]) * y[(size_t)r * 128 + d]) + bias[d];
  return relu ? fmaxf(v, 0.f) : v;
}

// ---- x2 = row-pool(relu-gcn-epi(level1)); y2 = d2.*(x2@W2); y2T bf16
__global__ __launch_bounds__(128) void epi_pool_gemm_kernel(const float* __restrict__ G,
                                                            const float* __restrict__ yB,
                                                            const float* __restrict__ rs1,
                                                            const float* __restrict__ diag1,
                                                            const float* __restrict__ b1,
                                                            const float* __restrict__ W,
                                                            const float* __restrict__ rs2,
                                                            const float* __restrict__ diag2,
                                                            float* __restrict__ y2B,
                                                            unsigned short* __restrict__ Y2T,
                                                            int n1, int M2) {
  __shared__ float xs[16][128];
  int r0 = blockIdx.x * 16;
  int d = threadIdx.x;
  #pragma unroll
  for (int i = 0; i < 16; ++i) {
    int rr = 2 * (r0 + i);
    float s = 0.f;
    #pragma unroll
    for (int a = 0; a < 4; ++a)
      s += epi_h(G, yB, rs1, diag1, b1, n1, (rr + a) & (n1 - 1), d, true);
    xs[i][d] = s;
  }
  __syncthreads();
  float acc[16];
  gemm16x128(xs, W, d, acc);
  short8v t0, t1;
  #pragma unroll
  for (int i = 0; i < 16; ++i) {
    int j = r0 + i;
    float dv = rsqrtf(fmaxf(rs2[j] - diag2[j] + 1.f, 1.f));
    float v = acc[i] * dv;
    y2B[(size_t)j * 128 + d] = v;
    if (i < 8) t0[i] = (short)f2bf(v); else t1[i - 8] = (short)f2bf(v);
  }
  *(short8v*)&Y2T[(size_t)d * M2 + r0] = t0;
  *(short8v*)&Y2T[(size_t)d * M2 + r0 + 8] = t1;
}

// ---- level-2 A@y2 (full K, 4 waves/block) with GCN-2 epilogue folded -> h2
__global__ __launch_bounds__(256) void mfma2_epi_kernel(const unsigned short* __restrict__ adj2h,
                                                        const unsigned short* __restrict__ y2T,
                                                        const float* __restrict__ y2B,
                                                        const float* __restrict__ rs2,
                                                        const float* __restrict__ diag2,
                                                        const float* __restrict__ b2,
                                                        float* __restrict__ h2) {
  int fid = blockIdx.x * 4 + (threadIdx.x >> 6);  // [0,512)
  int jt = fid & 63, nt = fid >> 6;
  int lane = threadIdx.x & 63, q = lane & 15, g = lane >> 4;
  const unsigned short* arow = adj2h + (size_t)(jt * 16 + q) * 1024;
  const unsigned short* brow = y2T + (size_t)(nt * 16 + q) * 1024;
  f32x4 acc = {0.f, 0.f, 0.f, 0.f};
  for (int k0 = 0; k0 < 1024; k0 += 32) {
    int ka = k0 + g * 8;
    short8v af = *(const short8v*)(arow + ka);
    short8v bf = *(const short8v*)(brow + ka);
    acc = mfma16(af, bf, acc);
  }
  #pragma unroll
  for (int r = 0; r < 4; ++r) {
    int row = jt * 16 + g * 4 + r, col = nt * 16 + q;
    float dv = rsqrtf(fmaxf(rs2[row] - diag2[row] + 1.f, 1.f));
    float v = dv * (acc[r] + (1.f - diag2[row]) * y2B[(size_t)row * 128 + col]) + b2[col];
    h2[(size_t)row * 128 + col] = v;
  }
}

__global__ __launch_bounds__(128) void colsum_kernel(const float* __restrict__ H,
                                                     float* __restrict__ partial, int rpb) {
  int d = threadIdx.x, b = blockIdx.x;
  float s = 0.f;
  for (int i = 0; i < rpb; ++i) s += H[(size_t)(b * rpb + i) * 128 + d];
  partial[(size_t)b * 128 + d] = s;
}

__global__ __launch_bounds__(128) void final_kernel(const float* __restrict__ partial, int nb,
                                                    const float* __restrict__ b2,
                                                    const float* __restrict__ Wlin,
                                                    const float* __restrict__ blin,
                                                    float* __restrict__ out) {
  int d = threadIdx.x;
  float cs = 0.f;
  for (int b = 0; b < nb; ++b) cs += partial[(size_t)b * 128 + d];
  // rows >=1024 of h2 are exactly b2 each (zero x2, identity-normalized diag)
  float mean = (cs + 1024.f * b2[d]) * (1.f / 2048.f);
  __shared__ float r0[128], r1[128];
  r0[d] = mean * Wlin[d];
  r1[d] = mean * Wlin[128 + d];
  __syncthreads();
  for (int s = 64; s > 0; s >>= 1) {
    if (d < s) { r0[d] += r0[d + s]; r1[d] += r1[d + s]; }
    __syncthreads();
  }
  if (d == 0) {
    float z0 = fmaxf(r0[0] + blin[0], 0.f);
    float z1 = fmaxf(r1[0] + blin[1], 0.f);
    float mz = fmaxf(z0, z1);
    float lse = mz + logf(__expf(z0 - mz) + __expf(z1 - mz));
    out[0] = z0 - lse;
    out[1] = z1 - lse;
  }
}

extern "C" void kernel_launch(void* const* d_in, const int* in_sizes, int n_in,
                              void* d_out, int out_size, void* d_ws, size_t ws_size,
                              hipStream_t stream) {
  const float* x      = (const float*)d_in[0];
  const float* eidx   = (const float*)d_in[1];
  const float* newadj = eidx + (size_t)4096 * 4096;  // edge_index[1]
  const float* ca1    = (const float*)d_in[3];
  const float* W1     = (const float*)d_in[4];
  const float* b1     = (const float*)d_in[5];
  const float* W2     = (const float*)d_in[6];
  const float* b2     = (const float*)d_in[7];
  const float* Wlin   = (const float*)d_in[8];
  const float* blin   = (const float*)d_in[9];
  float* out = (float*)d_out;

  if (ws_size < 32u * 1024u * 1024u) return;

  char* p = (char*)d_ws;
  auto alloc = [&](size_t bytes) -> char* {
    char* r = p; p += (bytes + 255) & ~(size_t)255; return r;
  };
  unsigned short* adj1h = (unsigned short*)alloc((size_t)2048 * 2048 * 2);
  float* d1raw = (float*)alloc(2048 * 4);
  float* diag1 = (float*)alloc(2048 * 4);
  float* x1b   = (float*)alloc((size_t)2048 * 128 * 4);
  unsigned short* QhB = (unsigned short*)alloc((size_t)2048 * 128 * 2);
  unsigned short* QlB = (unsigned short*)alloc((size_t)2048 * 128 * 2);
  unsigned short* KhB = (unsigned short*)alloc((size_t)4096 * 128 * 2);
  unsigned short* KlB = (unsigned short*)alloc((size_t)4096 * 128 * 2);
  unsigned short* VTB = (unsigned short*)alloc((size_t)4096 * 128 * 2);
  float* pmB   = (float*)alloc((size_t)2048 * 16 * 4);
  float* plB   = (float*)alloc((size_t)2048 * 16 * 4);
  unsigned short* pacc = (unsigned short*)alloc((size_t)2048 * 16 * 128 * 2);
  float* yB    = (float*)alloc((size_t)2048 * 128 * 4);
  unsigned short* yT = (unsigned short*)alloc((size_t)2048 * 128 * 2);
  float* G     = (float*)alloc((size_t)2 * 2048 * 128 * 4);
  unsigned short* adj2h = (unsigned short*)alloc((size_t)1024 * 1024 * 2);
  float* d2raw = (float*)alloc(1024 * 4);
  float* diag2 = (float*)alloc(1024 * 4);
  float* y2B   = (float*)alloc((size_t)1024 * 128 * 4);
  unsigned short* y2T = (unsigned short*)alloc((size_t)1024 * 128 * 2);
  float* h2    = (float*)alloc((size_t)1024 * 128 * 4);
  float* part  = (float*)alloc((size_t)16 * 128 * 4);

  // 1. pool_adj1 || K/V split+transpose || x1b+Q gemm
  mega1_kernel<<<2624, 256, 0, stream>>>(newadj, adj1h, d1raw, diag1,
                                         x, KhB, KlB, VTB, ca1, x1b, QhB, QlB);
  // 2. flash attention partials
  flash_kernel<<<2048, 64, 0, stream>>>(QhB, QlB, KhB, KlB, VTB, pacc, pmB, plB);
  // 3. combine -> x1 (LDS); y = d1 .* (x1 @ W1); yT
  combine_gemm_kernel<<<128, 128, 0, stream>>>(pacc, pmB, plB, x1b, W1, d1raw, diag1, yB, yT, 2048);
  // 4. G (2 partials) = adj1h @ y  ||  pool_adj2
  mega2_kernel<<<1536, 256, 0, stream>>>(adj1h, yT, G, adj2h, d2raw, diag2);
  // 5. h (inline) -> x2 = row-pool(h); y2 = d2 .* (x2 @ W2); y2T
  epi_pool_gemm_kernel<<<64, 128, 0, stream>>>(G, yB, d1raw, diag1, b1, W2, d2raw, diag2, y2B, y2T, 2048, 1024);
  // 6. h2 = gcn2-epi(adj2h @ y2)  (full-K, epilogue folded)
  mfma2_epi_kernel<<<128, 256, 0, stream>>>(adj2h, y2T, y2B, d2raw, diag2, b2, h2);
  // 7. column partial sums of h2
  colsum_kernel<<<16, 128, 0, stream>>>(h2, part, 64);
  // 8. mean + linear + relu + log_softmax
  final_kernel<<<1, 128, 0, stream>>>(part, 16, b2, Wlin, blin, out);
}